// Round 2
// baseline (99.653 us; speedup 1.0000x reference)
//
#include <hip/hip_runtime.h>

#define TLEN 2048
#define BROWS 2048
#define NSHIFT 31
#define MAXSH 15
#define BLOCK 256
#define EPSF 1e-8f

// stride-12 padded LDS index: 8-float groups at 12-dword stride.
// 12*tid dwords = 48*tid bytes -> 16B-aligned b128 reads; lane starts
// 12l mod 32 cover all 32 banks once per 8 lanes -> conflict-free b128.
__device__ __forceinline__ int padidx12(int k) { return 12 * (k >> 3) + (k & 7); }

// ---- DPP wave64 reductions (VALU pipe, zero DS ops) ----
template<int CTRL, int RMASK, bool BC>
__device__ __forceinline__ float dpp_mov(float v, float old) {
    return __int_as_float(__builtin_amdgcn_update_dpp(
        __float_as_int(old), __float_as_int(v), CTRL, RMASK, 0xF, BC));
}
// sum across 64 lanes; result valid in lane 63
__device__ __forceinline__ float wave_sum_dpp(float v) {
    v += dpp_mov<0x111, 0xF, true>(v, 0.f);   // row_shr:1
    v += dpp_mov<0x112, 0xF, true>(v, 0.f);   // row_shr:2
    v += dpp_mov<0x114, 0xF, true>(v, 0.f);   // row_shr:4
    v += dpp_mov<0x118, 0xF, true>(v, 0.f);   // row_shr:8  -> lane15 of each row
    v += dpp_mov<0x142, 0xA, true>(v, 0.f);   // row_bcast15 -> rows 1,3
    v += dpp_mov<0x143, 0xC, true>(v, 0.f);   // row_bcast31 -> rows 2,3; lane63 = total
    return v;
}
// max across 64 lanes; result valid in lane 63 (old=v so masked lanes are no-ops)
__device__ __forceinline__ float wave_max_dpp(float v) {
    v = fmaxf(v, dpp_mov<0x111, 0xF, false>(v, v));
    v = fmaxf(v, dpp_mov<0x112, 0xF, false>(v, v));
    v = fmaxf(v, dpp_mov<0x114, 0xF, false>(v, v));
    v = fmaxf(v, dpp_mov<0x118, 0xF, false>(v, v));
    v = fmaxf(v, dpp_mov<0x142, 0xA, false>(v, v));
    v = fmaxf(v, dpp_mov<0x143, 0xC, false>(v, v));
    return v;
}
// all-reduce sum within each 16-lane row via rotations (valid in all lanes)
__device__ __forceinline__ float row16_sum(float v) {
    v += dpp_mov<0x128, 0xF, true>(v, 0.f);   // row_ror:8
    v += dpp_mov<0x124, 0xF, true>(v, 0.f);   // row_ror:4
    v += dpp_mov<0x122, 0xF, true>(v, 0.f);   // row_ror:2
    v += dpp_mov<0x121, 0xF, true>(v, 0.f);   // row_ror:1
    return v;
}

// ---- xor-exchange pair reduce: one output register holds BOTH operands'
// xor-class sums in complementary lane sets (which half owns which operand is
// left implicit — identical across waves, and the consumer is slot-agnostic).
#if __has_builtin(__builtin_amdgcn_permlane32_swap)
__device__ __forceinline__ float pswap32_add(float x, float y) {
    auto r = __builtin_amdgcn_permlane32_swap(
        __float_as_uint(x), __float_as_uint(y), false, false);
    return __uint_as_float(r[0]) + __uint_as_float(r[1]);
}
#else
__device__ __forceinline__ float pswap32_add(float x, float y) {
    bool hi = (threadIdx.x & 32) != 0;
    float keep = hi ? y : x;
    float send = hi ? x : y;
    return keep + __shfl_xor(send, 32, 64);
}
#endif
#if __has_builtin(__builtin_amdgcn_permlane16_swap)
__device__ __forceinline__ float pswap16_add(float x, float y) {
    auto r = __builtin_amdgcn_permlane16_swap(
        __float_as_uint(x), __float_as_uint(y), false, false);
    return __uint_as_float(r[0]) + __uint_as_float(r[1]);
}
#else
__device__ __forceinline__ float pswap16_add(float x, float y) {
    bool hi = (threadIdx.x & 16) != 0;
    float keep = hi ? y : x;
    float send = hi ? x : y;
    return keep + __shfl_xor(send, 16, 64);
}
#endif

// smem layout (floats):
//   [0, 3120)      : stride-12 padded ext targets (260 groups)
//   [3120, 3248)   : wsum — 4 waves x 32 slots (one fully-reduced dot per slot)
//   [3248, 3264)   : rbuf — 4 waves x {sp,spp,st,stt}; reused for final mean
__global__ void __launch_bounds__(BLOCK, 4)
pearson_rows_kernel(const float* __restrict__ preds,
                    const float* __restrict__ targets,
                    float* __restrict__ row_best,
                    unsigned* __restrict__ ticket,
                    float* __restrict__ out)
{
    __shared__ float smem[3264];
    __shared__ int is_last;
    float* wsum = smem + 3120;
    float* rbuf = smem + 3248;

    const int tid  = threadIdx.x;
    const int wave = tid >> 6;
    const int lane = tid & 63;
    const int row  = blockIdx.x;
    const float* p_row = preds   + (size_t)row * TLEN;
    const float* t_row = targets + (size_t)row * TLEN;

    // ---- p: global -> registers (thread owns j in [8*tid, 8*tid+8)) ----
    float pc[8];
    {
        float4 a = ((const float4*)p_row)[2 * tid];
        float4 b = ((const float4*)p_row)[2 * tid + 1];
        pc[0] = a.x; pc[1] = a.y; pc[2] = a.z; pc[3] = a.w;
        pc[4] = b.x; pc[5] = b.y; pc[6] = b.z; pc[7] = b.w;
    }
    float sp = 0.f, spp = 0.f;
    #pragma unroll
    for (int i = 0; i < 8; ++i) { sp += pc[i]; spp = fmaf(pc[i], pc[i], spp); }

    // ---- t: coalesced load, row sums, stage ext into stride-12 LDS ----
    float st = 0.f, stt = 0.f;
    #pragma unroll
    for (int r = 0; r < 2; ++r) {
        int f4 = tid + r * BLOCK;
        float4 tv = ((const float4*)t_row)[f4];
        st  += tv.x + tv.y + tv.z + tv.w;
        stt = fmaf(tv.x, tv.x, stt); stt = fmaf(tv.y, tv.y, stt);
        stt = fmaf(tv.z, tv.z, stt); stt = fmaf(tv.w, tv.w, stt);
        int k = f4 * 4 + MAXSH;              // ext[k] = t[(k-15) mod T]
        smem[padidx12(k)]     = tv.x;
        smem[padidx12(k + 1)] = tv.y;
        smem[padidx12(k + 2)] = tv.z;
        smem[padidx12(k + 3)] = tv.w;
    }
    if (tid < MAXSH) {
        smem[padidx12(tid)] = t_row[TLEN - MAXSH + tid];
    } else if (tid >= 32 && tid < 32 + MAXSH) {
        int i = tid - 32;
        smem[padidx12(TLEN + MAXSH + i)] = t_row[i];
    }

    // ---- stats: DPP reduce (VALU), lane63 writes one float4 ----
    sp  = wave_sum_dpp(sp);
    spp = wave_sum_dpp(spp);
    st  = wave_sum_dpp(st);
    stt = wave_sum_dpp(stt);
    if (lane == 63) {
        *(float4*)(rbuf + wave * 4) = make_float4(sp, spp, st, stt);
    }
    __syncthreads();   // staging (and rbuf) visible

    // ---- window: 9x ds_read_b128 + 1x b64, conflict-free, pinned to VGPRs ----
    float w[38];
    {
        const float* g = smem + 12 * tid;
        #pragma unroll
        for (int q = 0; q < 4; ++q) {
            float4 a = *(const float4*)(g + 12 * q);
            float4 b = *(const float4*)(g + 12 * q + 4);
            w[8*q + 0] = a.x; w[8*q + 1] = a.y; w[8*q + 2] = a.z; w[8*q + 3] = a.w;
            w[8*q + 4] = b.x; w[8*q + 5] = b.y; w[8*q + 6] = b.z; w[8*q + 7] = b.w;
        }
        float4 c = *(const float4*)(g + 48);
        float2 e = *(const float2*)(g + 52);
        w[32] = c.x; w[33] = c.y; w[34] = c.z; w[35] = c.w;
        w[36] = e.x; w[37] = e.y;
        // compiler barrier: without it the loads legally sink into the FMA
        // loop (no clobber barrier anymore) -> 248 scalar ds_read_b32/thread
        #pragma unroll
        for (int d = 0; d < 38; ++d) asm volatile("" : "+v"(w[d]));
    }

    // ---- 31 raw circular dots: acc[s] = sum_m pc[m] * ext[8*tid + m + s] ----
    float acc[32];
    #pragma unroll
    for (int s = 0; s < NSHIFT; ++s) acc[s] = pc[0] * w[s];   // mul-init (no zero movs)
    #pragma unroll
    for (int m = 1; m < 8; ++m) {
        #pragma unroll
        for (int s = 0; s < NSHIFT; ++s) acc[s] = fmaf(pc[m], w[m + s], acc[s]);
    }
    // slot 31 duplicates shift 30: all 32 slots hold a VALID shift's dot, so the
    // final max needs no masking and the lane<->shift mapping can stay implicit.
    acc[31] = acc[30];

    // ---- reduce-scatter: 32 wave-sums in log2(64) exchange levels ----
    float r16[16];
    #pragma unroll
    for (int i = 0; i < 16; ++i) r16[i] = pswap32_add(acc[i], acc[i + 16]);
    float q[8];
    #pragma unroll
    for (int i = 0; i < 8; ++i) q[i] = pswap16_add(r16[i], r16[i + 8]);
    #pragma unroll
    for (int i = 0; i < 8; ++i) q[i] = row16_sum(q[i]);

    // cndmask-tree select q[lane&7] (compile-time indices only -> stays in VGPRs)
    {
        float s01 = (lane & 1) ? q[1] : q[0];
        float s23 = (lane & 1) ? q[3] : q[2];
        float s45 = (lane & 1) ? q[5] : q[4];
        float s67 = (lane & 1) ? q[7] : q[6];
        float s03 = (lane & 2) ? s23 : s01;
        float s47 = (lane & 2) ? s67 : s45;
        float sel = (lane & 4) ? s47 : s03;
        // slot = (lane&7) + 8*row; lanes l and l+8 hold the same value -> one writes.
        // 32 active lanes write 32 consecutive dwords: conflict-free.
        if (!(lane & 8)) wsum[wave * 32 + (lane & 7) + 8 * (lane >> 4)] = sel;
    }
    __syncthreads();

    // ---- final: wave 0. slot = lane&31 (lanes 32-63 duplicate -> maskless max) ----
    if (wave == 0) {
        int slot = lane & 31;
        float dot = wsum[slot] + wsum[32 + slot] + wsum[64 + slot] + wsum[96 + slot];
        float4 r0 = *(const float4*)(rbuf + 0);
        float4 r1 = *(const float4*)(rbuf + 4);
        float4 r2 = *(const float4*)(rbuf + 8);
        float4 r3 = *(const float4*)(rbuf + 12);
        float SP  = r0.x + r1.x + r2.x + r3.x;
        float SPP = r0.y + r1.y + r2.y + r3.y;
        float ST  = r0.z + r1.z + r2.z + r3.z;
        float STT = r0.w + r1.w + r2.w + r3.w;
        const float invT = 1.0f / TLEN;
        float mp = SP * invT, mt = ST * invT;
        float varp = SPP - (float)TLEN * mp * mp;
        float vart = STT - (float)TLEN * mt * mt;
        float corr = (float)TLEN * mp * mt;
        float pear = (dot - corr) * rsqrtf((varp + EPSF) * (vart + EPSF));
        float v = wave_max_dpp(pear);   // all 64 lanes valid: no masking
        if (lane == 63) {
            float best = fmaxf(v, -1.0f);
            // agent-scope (sc1) store: goes to the device-coherent point so other
            // XCDs can see it — no full-L2 writeback needed.
            __hip_atomic_store(row_best + row, best,
                               __ATOMIC_RELAXED, __HIP_MEMORY_SCOPE_AGENT);
            // store must COMPLETE (reach coherent point) before our ticket bump
            // becomes visible: drain vmem, then RMW.
            asm volatile("s_waitcnt vmcnt(0)" ::: "memory");
            unsigned old = __hip_atomic_fetch_add(ticket, 1u,
                               __ATOMIC_RELAXED, __HIP_MEMORY_SCOPE_AGENT);
            is_last = (old == BROWS - 1) ? 1 : 0;
        }
    }
    __syncthreads();    // is_last uniform across block (rbuf also free after this)

    // ---- last-arriving block performs the finalize inline (identical
    //      arithmetic order to the old 1-block kernel -> bit-identical) ----
    if (is_last) {
        __builtin_amdgcn_fence(__ATOMIC_ACQUIRE, "agent");  // see other XCDs' stores
        const float* rb = row_best;
        int i0 = 4 * tid;
        int i1 = 4 * (tid + BLOCK);
        float ax = __hip_atomic_load(rb + i0 + 0, __ATOMIC_RELAXED, __HIP_MEMORY_SCOPE_AGENT);
        float ay = __hip_atomic_load(rb + i0 + 1, __ATOMIC_RELAXED, __HIP_MEMORY_SCOPE_AGENT);
        float az = __hip_atomic_load(rb + i0 + 2, __ATOMIC_RELAXED, __HIP_MEMORY_SCOPE_AGENT);
        float aw = __hip_atomic_load(rb + i0 + 3, __ATOMIC_RELAXED, __HIP_MEMORY_SCOPE_AGENT);
        float bx = __hip_atomic_load(rb + i1 + 0, __ATOMIC_RELAXED, __HIP_MEMORY_SCOPE_AGENT);
        float by = __hip_atomic_load(rb + i1 + 1, __ATOMIC_RELAXED, __HIP_MEMORY_SCOPE_AGENT);
        float bz = __hip_atomic_load(rb + i1 + 2, __ATOMIC_RELAXED, __HIP_MEMORY_SCOPE_AGENT);
        float bw = __hip_atomic_load(rb + i1 + 3, __ATOMIC_RELAXED, __HIP_MEMORY_SCOPE_AGENT);
        float s = (ax + ay) + (az + aw) + (bx + by) + (bz + bw);
        s = wave_sum_dpp(s);
        if (lane == 63) rbuf[wave] = s;
        __syncthreads();
        if (tid == 0)
            out[0] = 1.0f - (rbuf[0] + rbuf[1] + rbuf[2] + rbuf[3]) * (1.0f / (float)BROWS);
    }
}

extern "C" void kernel_launch(void* const* d_in, const int* in_sizes, int n_in,
                              void* d_out, int out_size, void* d_ws, size_t ws_size,
                              hipStream_t stream) {
    const float* preds   = (const float*)d_in[0];
    const float* targets = (const float*)d_in[1];
    float* row_best  = (float*)d_ws;                               // 2048 floats
    unsigned* ticket = (unsigned*)((char*)d_ws + 2048 * sizeof(float));
    float* out       = (float*)d_out;
    // zero the ticket (workspace is poisoned each iteration); 4-byte memset node
    // is graph-capture-safe and cheaper than a serialized 1-block finalize kernel.
    hipMemsetAsync(ticket, 0, sizeof(unsigned), stream);
    pearson_rows_kernel<<<BROWS, BLOCK, 0, stream>>>(preds, targets, row_best, ticket, out);
}

// Round 3
// 77.726 us; speedup vs baseline: 1.2821x; 1.2821x over previous
//
#include <hip/hip_runtime.h>

#define TLEN 2048
#define BROWS 2048
#define NSHIFT 31
#define MAXSH 15
#define BLOCK 256
#define EPSF 1e-8f

// stride-12 padded LDS index: 8-float groups at 12-dword stride.
// 12*tid dwords = 48*tid bytes -> 16B-aligned b128 reads; lane starts
// 12l mod 32 cover all 32 banks once per 8 lanes -> conflict-free b128.
__device__ __forceinline__ int padidx12(int k) { return 12 * (k >> 3) + (k & 7); }

// ---- DPP wave64 reductions (VALU pipe, zero DS ops) ----
template<int CTRL, int RMASK, bool BC>
__device__ __forceinline__ float dpp_mov(float v, float old) {
    return __int_as_float(__builtin_amdgcn_update_dpp(
        __float_as_int(old), __float_as_int(v), CTRL, RMASK, 0xF, BC));
}
// sum across 64 lanes; result valid in lane 63
__device__ __forceinline__ float wave_sum_dpp(float v) {
    v += dpp_mov<0x111, 0xF, true>(v, 0.f);   // row_shr:1
    v += dpp_mov<0x112, 0xF, true>(v, 0.f);   // row_shr:2
    v += dpp_mov<0x114, 0xF, true>(v, 0.f);   // row_shr:4
    v += dpp_mov<0x118, 0xF, true>(v, 0.f);   // row_shr:8  -> lane15 of each row
    v += dpp_mov<0x142, 0xA, true>(v, 0.f);   // row_bcast15 -> rows 1,3
    v += dpp_mov<0x143, 0xC, true>(v, 0.f);   // row_bcast31 -> rows 2,3; lane63 = total
    return v;
}
// max across 64 lanes; result valid in lane 63 (old=v so masked lanes are no-ops)
__device__ __forceinline__ float wave_max_dpp(float v) {
    v = fmaxf(v, dpp_mov<0x111, 0xF, false>(v, v));
    v = fmaxf(v, dpp_mov<0x112, 0xF, false>(v, v));
    v = fmaxf(v, dpp_mov<0x114, 0xF, false>(v, v));
    v = fmaxf(v, dpp_mov<0x118, 0xF, false>(v, v));
    v = fmaxf(v, dpp_mov<0x142, 0xA, false>(v, v));
    v = fmaxf(v, dpp_mov<0x143, 0xC, false>(v, v));
    return v;
}
// all-reduce sum within each 16-lane row via rotations (valid in all lanes)
__device__ __forceinline__ float row16_sum(float v) {
    v += dpp_mov<0x128, 0xF, true>(v, 0.f);   // row_ror:8
    v += dpp_mov<0x124, 0xF, true>(v, 0.f);   // row_ror:4
    v += dpp_mov<0x122, 0xF, true>(v, 0.f);   // row_ror:2
    v += dpp_mov<0x121, 0xF, true>(v, 0.f);   // row_ror:1
    return v;
}

// ---- xor-exchange pair reduce: one output register holds BOTH operands'
// xor-class sums in complementary lane sets (which half owns which operand is
// left implicit — identical across waves, and the consumer is slot-agnostic).
#if __has_builtin(__builtin_amdgcn_permlane32_swap)
__device__ __forceinline__ float pswap32_add(float x, float y) {
    auto r = __builtin_amdgcn_permlane32_swap(
        __float_as_uint(x), __float_as_uint(y), false, false);
    return __uint_as_float(r[0]) + __uint_as_float(r[1]);
}
#else
__device__ __forceinline__ float pswap32_add(float x, float y) {
    bool hi = (threadIdx.x & 32) != 0;
    float keep = hi ? y : x;
    float send = hi ? x : y;
    return keep + __shfl_xor(send, 32, 64);
}
#endif
#if __has_builtin(__builtin_amdgcn_permlane16_swap)
__device__ __forceinline__ float pswap16_add(float x, float y) {
    auto r = __builtin_amdgcn_permlane16_swap(
        __float_as_uint(x), __float_as_uint(y), false, false);
    return __uint_as_float(r[0]) + __uint_as_float(r[1]);
}
#else
__device__ __forceinline__ float pswap16_add(float x, float y) {
    bool hi = (threadIdx.x & 16) != 0;
    float keep = hi ? y : x;
    float send = hi ? x : y;
    return keep + __shfl_xor(send, 16, 64);
}
#endif

// smem layout (floats):
//   [0, 3120)      : stride-12 padded ext targets (260 groups)
//   [3120, 3248)   : wsum — 4 waves x 32 slots (one fully-reduced dot per slot)
//   [3248, 3264)   : rbuf — 4 waves x {sp,spp,st,stt}
__global__ void __launch_bounds__(BLOCK, 4)
pearson_rows_kernel(const float* __restrict__ preds,
                    const float* __restrict__ targets,
                    float* __restrict__ row_best)
{
    __shared__ float smem[3264];
    float* wsum = smem + 3120;
    float* rbuf = smem + 3248;

    const int tid  = threadIdx.x;
    const int wave = tid >> 6;
    const int lane = tid & 63;
    const int row  = blockIdx.x;
    const float* p_row = preds   + (size_t)row * TLEN;
    const float* t_row = targets + (size_t)row * TLEN;

    // ---- p: global -> registers (thread owns j in [8*tid, 8*tid+8)) ----
    float pc[8];
    {
        float4 a = ((const float4*)p_row)[2 * tid];
        float4 b = ((const float4*)p_row)[2 * tid + 1];
        pc[0] = a.x; pc[1] = a.y; pc[2] = a.z; pc[3] = a.w;
        pc[4] = b.x; pc[5] = b.y; pc[6] = b.z; pc[7] = b.w;
    }
    float sp = 0.f, spp = 0.f;
    #pragma unroll
    for (int i = 0; i < 8; ++i) { sp += pc[i]; spp = fmaf(pc[i], pc[i], spp); }

    // ---- t: coalesced load, row sums, stage ext into stride-12 LDS ----
    float st = 0.f, stt = 0.f;
    #pragma unroll
    for (int r = 0; r < 2; ++r) {
        int f4 = tid + r * BLOCK;
        float4 tv = ((const float4*)t_row)[f4];
        st  += tv.x + tv.y + tv.z + tv.w;
        stt = fmaf(tv.x, tv.x, stt); stt = fmaf(tv.y, tv.y, stt);
        stt = fmaf(tv.z, tv.z, stt); stt = fmaf(tv.w, tv.w, stt);
        int k = f4 * 4 + MAXSH;              // ext[k] = t[(k-15) mod T]
        smem[padidx12(k)]     = tv.x;
        smem[padidx12(k + 1)] = tv.y;
        smem[padidx12(k + 2)] = tv.z;
        smem[padidx12(k + 3)] = tv.w;
    }
    if (tid < MAXSH) {
        smem[padidx12(tid)] = t_row[TLEN - MAXSH + tid];
    } else if (tid >= 32 && tid < 32 + MAXSH) {
        int i = tid - 32;
        smem[padidx12(TLEN + MAXSH + i)] = t_row[i];
    }

    // ---- stats: DPP reduce (VALU), lane63 writes one float4 ----
    sp  = wave_sum_dpp(sp);
    spp = wave_sum_dpp(spp);
    st  = wave_sum_dpp(st);
    stt = wave_sum_dpp(stt);
    if (lane == 63) {
        *(float4*)(rbuf + wave * 4) = make_float4(sp, spp, st, stt);
    }
    __syncthreads();   // staging (and rbuf) visible

    // ---- window: 9x ds_read_b128 + 1x b64, conflict-free, pinned to VGPRs ----
    float w[38];
    {
        const float* g = smem + 12 * tid;
        #pragma unroll
        for (int q = 0; q < 4; ++q) {
            float4 a = *(const float4*)(g + 12 * q);
            float4 b = *(const float4*)(g + 12 * q + 4);
            w[8*q + 0] = a.x; w[8*q + 1] = a.y; w[8*q + 2] = a.z; w[8*q + 3] = a.w;
            w[8*q + 4] = b.x; w[8*q + 5] = b.y; w[8*q + 6] = b.z; w[8*q + 7] = b.w;
        }
        float4 c = *(const float4*)(g + 48);
        float2 e = *(const float2*)(g + 52);
        w[32] = c.x; w[33] = c.y; w[34] = c.z; w[35] = c.w;
        w[36] = e.x; w[37] = e.y;
        // compiler barrier: without it the loads legally sink into the FMA
        // loop (no clobber barrier anymore) -> 248 scalar ds_read_b32/thread
        #pragma unroll
        for (int d = 0; d < 38; ++d) asm volatile("" : "+v"(w[d]));
    }

    // ---- 31 raw circular dots: acc[s] = sum_m pc[m] * ext[8*tid + m + s] ----
    float acc[32];
    #pragma unroll
    for (int s = 0; s < NSHIFT; ++s) acc[s] = pc[0] * w[s];   // mul-init (no zero movs)
    #pragma unroll
    for (int m = 1; m < 8; ++m) {
        #pragma unroll
        for (int s = 0; s < NSHIFT; ++s) acc[s] = fmaf(pc[m], w[m + s], acc[s]);
    }
    // slot 31 duplicates shift 30: all 32 slots hold a VALID shift's dot, so the
    // final max needs no masking and the lane<->shift mapping can stay implicit.
    acc[31] = acc[30];

    // ---- reduce-scatter: 32 wave-sums in log2(64) exchange levels ----
    // xor32: 16 swaps+adds; xor16: 8 swaps+adds; xor8/4/2/1: row rotations.
    // Afterwards q[j] (j in [0,8)) holds, per 16-lane row, the full wave sum of
    // one of the 4 shifts congruent to j mod 8 (bijective over rows).
    float r16[16];
    #pragma unroll
    for (int i = 0; i < 16; ++i) r16[i] = pswap32_add(acc[i], acc[i + 16]);
    float q[8];
    #pragma unroll
    for (int i = 0; i < 8; ++i) q[i] = pswap16_add(r16[i], r16[i + 8]);
    #pragma unroll
    for (int i = 0; i < 8; ++i) q[i] = row16_sum(q[i]);

    // cndmask-tree select q[lane&7] (compile-time indices only -> stays in VGPRs)
    {
        float s01 = (lane & 1) ? q[1] : q[0];
        float s23 = (lane & 1) ? q[3] : q[2];
        float s45 = (lane & 1) ? q[5] : q[4];
        float s67 = (lane & 1) ? q[7] : q[6];
        float s03 = (lane & 2) ? s23 : s01;
        float s47 = (lane & 2) ? s67 : s45;
        float sel = (lane & 4) ? s47 : s03;
        // slot = (lane&7) + 8*row; lanes l and l+8 hold the same value -> one writes.
        // 32 active lanes write 32 consecutive dwords: conflict-free.
        if (!(lane & 8)) wsum[wave * 32 + (lane & 7) + 8 * (lane >> 4)] = sel;
    }
    __syncthreads();

    // ---- final: wave 0. slot = lane&31 (lanes 32-63 duplicate -> maskless max) ----
    if (wave == 0) {
        int slot = lane & 31;
        float dot = wsum[slot] + wsum[32 + slot] + wsum[64 + slot] + wsum[96 + slot];
        float4 r0 = *(const float4*)(rbuf + 0);
        float4 r1 = *(const float4*)(rbuf + 4);
        float4 r2 = *(const float4*)(rbuf + 8);
        float4 r3 = *(const float4*)(rbuf + 12);
        float SP  = r0.x + r1.x + r2.x + r3.x;
        float SPP = r0.y + r1.y + r2.y + r3.y;
        float ST  = r0.z + r1.z + r2.z + r3.z;
        float STT = r0.w + r1.w + r2.w + r3.w;
        const float invT = 1.0f / TLEN;
        float mp = SP * invT, mt = ST * invT;
        float varp = SPP - (float)TLEN * mp * mp;
        float vart = STT - (float)TLEN * mt * mt;
        float corr = (float)TLEN * mp * mt;
        float pear = (dot - corr) * rsqrtf((varp + EPSF) * (vart + EPSF));
        float v = wave_max_dpp(pear);   // all 64 lanes valid: no masking
        if (lane == 63) row_best[row] = fmaxf(v, -1.0f);
    }
}

// 1 block: mean over 2048 per-row bests, write final loss
__global__ void __launch_bounds__(BLOCK)
pearson_finalize_kernel(const float* __restrict__ row_best, float* __restrict__ out)
{
    __shared__ float r[4];
    const int tid = threadIdx.x, wave = tid >> 6, lane = tid & 63;
    float4 a = ((const float4*)row_best)[tid];
    float4 b = ((const float4*)row_best)[tid + BLOCK];
    float s = (a.x + a.y) + (a.z + a.w) + (b.x + b.y) + (b.z + b.w);
    s = wave_sum_dpp(s);
    if (lane == 63) r[wave] = s;
    __syncthreads();
    if (tid == 0)
        out[0] = 1.0f - (r[0] + r[1] + r[2] + r[3]) * (1.0f / (float)BROWS);
}

extern "C" void kernel_launch(void* const* d_in, const int* in_sizes, int n_in,
                              void* d_out, int out_size, void* d_ws, size_t ws_size,
                              hipStream_t stream) {
    const float* preds   = (const float*)d_in[0];
    const float* targets = (const float*)d_in[1];
    float* row_best = (float*)d_ws;          // 2048 floats of scratch
    float* out      = (float*)d_out;
    pearson_rows_kernel<<<BROWS, BLOCK, 0, stream>>>(preds, targets, row_best);
    pearson_finalize_kernel<<<1, BLOCK, 0, stream>>>(row_best, out);
}